// Round 20
// baseline (60849.011 us; speedup 1.0000x reference)
//
#include <hip/hip_runtime.h>
#include <math.h>

// ---------------- shared exact-math helpers ----------------

// Bit-replica of Eigen generic_fast_tanh_float == XLA EmitTanh<F32> (jax CPU).
// DO NOT MODIFY: bit-matched to the reference trajectory (round 10 pass).
__device__ __forceinline__ float tanh_xla(float x) {
    const float plus_clamp = 7.90531110763549805f;
    float xc = fminf(fmaxf(x, -plus_clamp), plus_clamp);
    float x2 = xc * xc;
    float p = fmaf(x2, -2.76076847742355e-16f, 2.00018790482477e-13f);
    p = fmaf(x2, p, -8.60467152213735e-11f);
    p = fmaf(x2, p,  5.12229709037114e-08f);
    p = fmaf(x2, p,  1.48572235717979e-05f);
    p = fmaf(x2, p,  6.37261928875436e-04f);
    p = fmaf(x2, p,  4.89352455891786e-03f);
    p = xc * p;
    float q = fmaf(x2, 1.19825839466702e-06f, 1.18534705686654e-04f);
    q = fmaf(x2, q, 2.26843463243900e-03f);
    q = fmaf(x2, q, 4.89352518554385e-03f);
    float r = p / q;
    return (fabsf(x) < 0.0004f) ? x : r;
}

// ---------------- fc1 / fc2: r13-exact tiled GEMM (known-good, ~141us) ----------------

#define Hdim 256
#define GBM 64
#define GKP 32
#define GNP (Hdim / GKP)
#define GTHREADS 512
#define AS_LD 68
#define WS_LD 260

template<bool TRANS_B, bool BIAS, bool TANH>
__global__ __launch_bounds__(GTHREADS, 1)
void gemm256(const float* A, const float* W, const float* bias, float* C) {
    __shared__ __align__(16) float As[GKP][AS_LD];
    __shared__ __align__(16) float Ws[GKP][WS_LD];

    const int  t    = threadIdx.x;
    const long row0 = (long)blockIdx.x * GBM;
    const int  tm   = t & 15;
    const int  tn   = t >> 4;

    const int ar  = t >> 3;
    const int akq = t & 7;
    const float* Abase = A + (row0 + ar) * Hdim + akq * 4;

    float acc[4][8];
#pragma unroll
    for (int i = 0; i < 4; ++i)
#pragma unroll
        for (int j = 0; j < 8; ++j) acc[i][j] = 0.f;

    auto load_panel = [&](int p, float4& a, float4 (&w)[4]) {
        const int k0 = p * GKP;
        a = *reinterpret_cast<const float4*>(Abase + k0);
        if (TRANS_B) {
#pragma unroll
            for (int q = 0; q < 4; ++q) {
                int c = q * GTHREADS + t;
                int wn = c >> 3, wkq = c & 7;
                w[q] = *reinterpret_cast<const float4*>(W + (long)wn * Hdim + k0 + wkq * 4);
            }
        } else {
#pragma unroll
            for (int q = 0; q < 4; ++q) {
                int c = q * GTHREADS + t;
                int wk = c >> 6, wn4 = c & 63;
                w[q] = *reinterpret_cast<const float4*>(W + (long)(k0 + wk) * Hdim + wn4 * 4);
            }
        }
    };

    auto store_panel = [&](const float4& a, const float4 (&w)[4]) {
        const float* af = reinterpret_cast<const float*>(&a);
#pragma unroll
        for (int i = 0; i < 4; ++i) As[akq * 4 + i][ar] = af[i];
        if (TRANS_B) {
#pragma unroll
            for (int q = 0; q < 4; ++q) {
                int c = q * GTHREADS + t;
                int wn = c >> 3, wkq = c & 7;
                const float* wf = reinterpret_cast<const float*>(&w[q]);
#pragma unroll
                for (int i = 0; i < 4; ++i) Ws[wkq * 4 + i][wn] = wf[i];
            }
        } else {
#pragma unroll
            for (int q = 0; q < 4; ++q) {
                int c = q * GTHREADS + t;
                int wk = c >> 6, wn4 = c & 63;
                *reinterpret_cast<float4*>(&Ws[wk][wn4 * 4]) = w[q];
            }
        }
    };

    {
        float4 a0; float4 w0[4];
        load_panel(0, a0, w0);
        store_panel(a0, w0);
    }
    __syncthreads();

#pragma unroll 1
    for (int p = 0; p < GNP; ++p) {
        float4 a2; float4 w2[4];
        const bool more = (p + 1 < GNP);
        if (more) load_panel(p + 1, a2, w2);

#pragma unroll 2
        for (int k = 0; k < GKP; ++k) {
            float4 av = *reinterpret_cast<const float4*>(&As[k][tm * 4]);
            float4 wa = *reinterpret_cast<const float4*>(&Ws[k][tn * 8]);
            float4 wb = *reinterpret_cast<const float4*>(&Ws[k][tn * 8 + 4]);
            const float aa[4] = {av.x, av.y, av.z, av.w};
            const float ww[8] = {wa.x, wa.y, wa.z, wa.w, wb.x, wb.y, wb.z, wb.w};
#pragma unroll
            for (int i = 0; i < 4; ++i)
#pragma unroll
                for (int j = 0; j < 8; ++j)
                    acc[i][j] = fmaf(aa[i], ww[j], acc[i][j]);
        }

        if (more) {
            __syncthreads();
            store_panel(a2, w2);
            __syncthreads();
        }
    }

    float bv[8];
    if (BIAS) {
        float4 b0 = *reinterpret_cast<const float4*>(bias + tn * 8);
        float4 b1 = *reinterpret_cast<const float4*>(bias + tn * 8 + 4);
        bv[0] = b0.x; bv[1] = b0.y; bv[2] = b0.z; bv[3] = b0.w;
        bv[4] = b1.x; bv[5] = b1.y; bv[6] = b1.z; bv[7] = b1.w;
    }

#pragma unroll
    for (int i = 0; i < 4; ++i) {
        long r = row0 + tm * 4 + i;
        float o[8];
#pragma unroll
        for (int j = 0; j < 8; ++j) {
            float v = acc[i][j];
            if (BIAS) v += bv[j];
            if (TANH) v = tanh_xla(v);
            o[j] = v;
        }
        float4* dst = reinterpret_cast<float4*>(C + r * Hdim + tn * 8);
        dst[0] = make_float4(o[0], o[1], o[2], o[3]);
        dst[1] = make_float4(o[4], o[5], o[6], o[7]);
    }
}

// ---------------- recurrence core: lane=row + depth-2 W-row register prefetch ----------------
// r16-r19 forensics: every variant (LDS / VMEM / SMEM W paths) lands at ~18 ms
// because the W[k,:] load is SERIALIZED against each k's FMAs (one ~400-cyc L2
// latency exposed per k, only 4-way wave-overlapped). Fix: two register buffers;
// FMA row k from buf[k&1], then immediately issue loads for row k+2 into it.
// Compiler emits fine-grained vmcnt (m97 behavior); the ~140-cyc own-wave issue
// between load and use + 3 other waves absorb the latency.
// Math unchanged: ascending-k fmaf chain per acc -> bit-identical trajectory.
#define RBM 64
#define RLD 68

__global__ __launch_bounds__(512, 2)
void rnn_core(const float* __restrict__ hIn, const float* __restrict__ Whh,
              float* __restrict__ hOut) {
    __shared__ __align__(16) float Hs[Hdim][RLD];   // 69,632 B: h, [k][m]

    const int  t    = threadIdx.x;
    const long row0 = (long)blockIdx.x * RBM;
    const int  lane = t & 63;
    const int  col0 = (t >> 6) * 32;                // wave's 32-col slice

    // stage h0 rows into Hs[k][m]
    {
        const int r  = t >> 3;
        const int kq = t & 7;
        const float* src = hIn + (row0 + r) * Hdim + kq * 4;
#pragma unroll
        for (int q = 0; q < 8; ++q) {
            float4 v = *reinterpret_cast<const float4*>(src + q * 32);
            const int k = q * 32 + kq * 4;
            Hs[k + 0][r] = v.x;
            Hs[k + 1][r] = v.y;
            Hs[k + 2][r] = v.z;
            Hs[k + 3][r] = v.w;
        }
    }
    __syncthreads();

    // wave-uniform W row pointers, float4 granularity
    const float4* Wv = reinterpret_cast<const float4*>(Whh) + (col0 >> 2);  // row 0, this slice

    float acc[32];
    float4 wA[8], wB[8];            // W rows k (A) and k+1 (B): 64 VGPRs

    auto loadrow = [&](float4 (&buf)[8], int row) {
        const float4* p = Wv + (long)row * (Hdim / 4);
#pragma unroll
        for (int q = 0; q < 8; ++q) buf[q] = p[q];
    };

#pragma unroll 1
    for (int s = 0; s < 128; ++s) {
#pragma unroll
        for (int j = 0; j < 32; ++j) acc[j] = 0.f;

        loadrow(wA, 0);
        loadrow(wB, 1);

#pragma unroll 1
        for (int k = 0; k < Hdim; k += 2) {
            {
                const float a = Hs[k][lane];
                const float* wf = reinterpret_cast<const float*>(wA);
#pragma unroll
                for (int j = 0; j < 32; ++j)
                    acc[j] = fmaf(a, wf[j], acc[j]);      // ascending-k chain (row k)
                loadrow(wA, (k + 2) & 255);               // prefetch row k+2 (wraps: harmless)
            }
            {
                const float a = Hs[k + 1][lane];
                const float* wf = reinterpret_cast<const float*>(wB);
#pragma unroll
                for (int j = 0; j < 32; ++j)
                    acc[j] = fmaf(a, wf[j], acc[j]);      // row k+1
                loadrow(wB, (k + 3) & 255);               // prefetch row k+3
            }
        }

#pragma unroll
        for (int j = 0; j < 32; ++j) acc[j] = tanh_xla(acc[j]);

        __syncthreads();                    // all Hs reads of this step done
#pragma unroll
        for (int j = 0; j < 32; ++j)
            Hs[col0 + j][lane] = acc[j];    // h' back to LDS ([k][m])
        __syncthreads();                    // h' visible for next step
    }

    // final h -> global (acc holds h_128 for row=lane, cols col0..col0+31)
    float* dst = hOut + (row0 + lane) * Hdim + col0;
#pragma unroll
    for (int j = 0; j < 8; ++j)
        *reinterpret_cast<float4*>(dst + j * 4) =
            make_float4(acc[j * 4 + 0], acc[j * 4 + 1], acc[j * 4 + 2], acc[j * 4 + 3]);
}

// ---------------- launch ----------------

extern "C" void kernel_launch(void* const* d_in, const int* in_sizes, int n_in,
                              void* d_out, int out_size, void* d_ws, size_t ws_size,
                              hipStream_t stream) {
    const float* x     = (const float*)d_in[0];
    const float* W_hh  = (const float*)d_in[1];
    const float* fc1_w = (const float*)d_in[2];
    const float* fc1_b = (const float*)d_in[3];
    const float* fc2_w = (const float*)d_in[4];
    const float* fc2_b = (const float*)d_in[5];
    // d_in[6] = steps (device scalar); fixed at 128 per the reference.

    const int B = in_sizes[0] / Hdim;      // 65536
    float* out = (float*)d_out;            // [B][256]
    float* h   = out + (long)B * Hdim;     // [B][256] second tuple output

    // h0 = x @ fc1_w^T + fc1_b   (r13-exact path)
    gemm256<true, true, false><<<dim3(B / GBM), dim3(GTHREADS), 0, stream>>>(x, fc1_w, fc1_b, h);
    // 128 recurrence steps, h LDS-resident, W depth-2 register-prefetched
    rnn_core<<<dim3(B / RBM), dim3(512), 0, stream>>>(h, W_hh, h);
    // out = h @ fc2_w^T + fc2_b
    gemm256<true, true, false><<<dim3(B / GBM), dim3(GTHREADS), 0, stream>>>(h, fc2_w, fc2_b, out);
}

// Round 21
// 13313.211 us; speedup vs baseline: 4.5706x; 4.5706x over previous
//
#include <hip/hip_runtime.h>
#include <math.h>

#define Hd 256
#define BM 128
#define KP 16
#define NP 16              // 256/16 K-panels
#define THREADS 512
#define HLD 68             // Hs half leading dim (64+4): 2-way-max bank aliasing
#define WLD 260            // Wp leading dim (256+4)

// Bit-replica of Eigen generic_fast_tanh_float == XLA EmitTanh<F32> (jax CPU).
// DO NOT MODIFY: bit-matched to the reference trajectory (round 10 pass).
__device__ __forceinline__ float tanh_xla(float x) {
    const float plus_clamp = 7.90531110763549805f;
    float xc = fminf(fmaxf(x, -plus_clamp), plus_clamp);
    float x2 = xc * xc;
    float p = fmaf(x2, -2.76076847742355e-16f, 2.00018790482477e-13f);
    p = fmaf(x2, p, -8.60467152213735e-11f);
    p = fmaf(x2, p,  5.12229709037114e-08f);
    p = fmaf(x2, p,  1.48572235717979e-05f);
    p = fmaf(x2, p,  6.37261928875436e-04f);
    p = fmaf(x2, p,  4.89352455891786e-03f);
    p = xc * p;
    float q = fmaf(x2, 1.19825839466702e-06f, 1.18534705686654e-04f);
    q = fmaf(x2, q, 2.26843463243900e-03f);
    q = fmaf(x2, q, 4.89352518554385e-03f);
    float r = p / q;
    return (fabsf(x) < 0.0004f) ? x : r;
}

// Fully fused RNN, 8x8-tile variant. r16's cycle model: the CU LDS pipe was the
// binding resource (768 b128-reads per wave-step for 32 FMAs each). This kernel:
// BM=128, thread tile 8x8 (4 rows in Hs0 + 4 in Hs1 x 8 cols) -> 4 b128 reads
// per 64 FMAs (1.5x less LDS/work), 512 blocks -> 2 CU-rounds (was 4).
// Hs0/Hs1 split keeps all LDS ops at <=2-way aliasing (free, m136).
// W: single 16-row LDS panel, reg-prefetched (T14). Race fix vs r16: barrier
// between last-panel compute and the Hs writeback.
// Per-element math: strict ascending-k fmaf chain + single bias add + tanh_xla
// -> bit-identical to r10/r13/r16 (absmax 0.06347656).
__global__ __launch_bounds__(THREADS, 1)
void rnn_fused(const float* __restrict__ x, const float* __restrict__ Whh,
               const float* __restrict__ fc1w, const float* __restrict__ fc1b,
               const float* __restrict__ fc2w, const float* __restrict__ fc2b,
               float* __restrict__ outF, float* __restrict__ hF) {
    __shared__ __align__(16) float Hs0[Hd][HLD];   // rows 0..63   [k][m] 69,632 B
    __shared__ __align__(16) float Hs1[Hd][HLD];   // rows 64..127 [k][m] 69,632 B
    __shared__ __align__(16) float Wp[KP][WLD];    // W panel 16,640 B  (total 155,904)

    const int  t    = threadIdx.x;
    const long row0 = (long)blockIdx.x * BM;
    const int  tm   = t & 15;      // row group: rows tm*4..+3 (low) and +64 (high)
    const int  tn   = t >> 4;      // col group: cols tn*8..+7

    // ---- stage x block rows into Hs0/Hs1 ([k][m] transpose) ----
    {
        const int r  = t >> 2;          // 0..127
        const int kq = (t & 3) * 4;     // 0,4,8,12
        float (*H)[HLD] = (r < 64) ? Hs0 : Hs1;
        const int m = r & 63;
        const float* src = x + (row0 + r) * Hd + kq;
#pragma unroll
        for (int q = 0; q < 16; ++q) {
            float4 v = *reinterpret_cast<const float4*>(src + q * 16);
            const int k = q * 16 + kq;
            H[k + 0][m] = v.x;
            H[k + 1][m] = v.y;
            H[k + 2][m] = v.z;
            H[k + 3][m] = v.w;
        }
    }
    __syncthreads();

    float accL[4][8], accH[4][8];
    float4 pf0, pf1;                 // W panel prefetch (2 float4/thread)

    // --- W panel staging: no-trans (Whh) ---
    auto ld_nt = [&](const float* W, int p) {
        const int k0 = p * KP;
        int c0 = t;           int wk0 = c0 >> 6, wn0 = c0 & 63;
        int c1 = 512 + t;     int wk1 = c1 >> 6, wn1 = c1 & 63;
        pf0 = *reinterpret_cast<const float4*>(W + (long)(k0 + wk0) * Hd + wn0 * 4);
        pf1 = *reinterpret_cast<const float4*>(W + (long)(k0 + wk1) * Hd + wn1 * 4);
    };
    auto st_nt = [&]() {
        int c0 = t;           int wk0 = c0 >> 6, wn0 = c0 & 63;
        int c1 = 512 + t;     int wk1 = c1 >> 6, wn1 = c1 & 63;
        *reinterpret_cast<float4*>(&Wp[wk0][wn0 * 4]) = pf0;
        *reinterpret_cast<float4*>(&Wp[wk1][wn1 * 4]) = pf1;
    };
    // --- W panel staging: trans (fc1_w / fc2_w, torch Linear W[n][k]) ---
    auto ld_t = [&](const float* W, int p) {
        const int k0 = p * KP;
        int c0 = t;           int n0 = c0 >> 2, kq0 = (c0 & 3) * 4;
        int c1 = 512 + t;     int n1 = c1 >> 2, kq1 = (c1 & 3) * 4;
        pf0 = *reinterpret_cast<const float4*>(W + (long)n0 * Hd + k0 + kq0);
        pf1 = *reinterpret_cast<const float4*>(W + (long)n1 * Hd + k0 + kq1);
    };
    auto st_t = [&]() {
        int c0 = t;           int n0 = c0 >> 2, kq0 = (c0 & 3) * 4;
        int c1 = 512 + t;     int n1 = c1 >> 2, kq1 = (c1 & 3) * 4;
        const float* f0 = reinterpret_cast<const float*>(&pf0);
        const float* f1 = reinterpret_cast<const float*>(&pf1);
#pragma unroll
        for (int i = 0; i < 4; ++i) Wp[kq0 + i][n0] = f0[i];
#pragma unroll
        for (int i = 0; i < 4; ++i) Wp[kq1 + i][n1] = f1[i];
    };

    auto zero_acc = [&]() {
#pragma unroll
        for (int i = 0; i < 4; ++i)
#pragma unroll
            for (int j = 0; j < 8; ++j) { accL[i][j] = 0.f; accH[i][j] = 0.f; }
    };

    // strict ascending-k FMA chain; 4 b128 reads feed 64 FMAs
    auto compute_panel = [&](int kbase) {
#pragma unroll 2
        for (int kk = 0; kk < KP; ++kk) {
            float4 aL = *reinterpret_cast<const float4*>(&Hs0[kbase + kk][tm * 4]);
            float4 aH = *reinterpret_cast<const float4*>(&Hs1[kbase + kk][tm * 4]);
            float4 w0 = *reinterpret_cast<const float4*>(&Wp[kk][tn * 8]);
            float4 w1 = *reinterpret_cast<const float4*>(&Wp[kk][tn * 8 + 4]);
            const float al[4] = {aL.x, aL.y, aL.z, aL.w};
            const float ah[4] = {aH.x, aH.y, aH.z, aH.w};
            const float ww[8] = {w0.x, w0.y, w0.z, w0.w, w1.x, w1.y, w1.z, w1.w};
#pragma unroll
            for (int i = 0; i < 4; ++i)
#pragma unroll
                for (int j = 0; j < 8; ++j) {
                    accL[i][j] = fmaf(al[i], ww[j], accL[i][j]);
                    accH[i][j] = fmaf(ah[i], ww[j], accH[i][j]);
                }
        }
    };

    // one GEMM pass: ends with a barrier (safe to overwrite Hs after). Single
    // Wp buffer: compute p; barrier; write p+1 (prefetched during compute);
    // barrier. unroll 1 so staging loads aren't hoisted (r10 lesson).
    auto run_nt = [&](const float* W) {
        zero_acc();
        ld_nt(W, 0); st_nt();
        __syncthreads();
#pragma unroll 1
        for (int p = 0; p < NP; ++p) {
            const bool more = (p + 1 < NP);
            if (more) ld_nt(W, p + 1);     // overlap global latency with compute
            compute_panel(p * KP);
            __syncthreads();               // all reads of panel p (and, at p=15, of Hs) done
            if (more) { st_nt(); __syncthreads(); }
        }
    };
    auto run_t = [&](const float* W) {
        zero_acc();
        ld_t(W, 0); st_t();
        __syncthreads();
#pragma unroll 1
        for (int p = 0; p < NP; ++p) {
            const bool more = (p + 1 < NP);
            if (more) ld_t(W, p + 1);
            compute_panel(p * KP);
            __syncthreads();
            if (more) { st_t(); __syncthreads(); }
        }
    };

    auto writeback_h = [&]() {   // Hs := acc ([k][m]); caller barriers after
#pragma unroll
        for (int j = 0; j < 8; ++j) {
            *reinterpret_cast<float4*>(&Hs0[tn * 8 + j][tm * 4]) =
                make_float4(accL[0][j], accL[1][j], accL[2][j], accL[3][j]);
            *reinterpret_cast<float4*>(&Hs1[tn * 8 + j][tm * 4]) =
                make_float4(accH[0][j], accH[1][j], accH[2][j], accH[3][j]);
        }
    };

    // ---- fc1: h0 = x @ fc1_w^T + fc1_b ----
    run_t(fc1w);
    {
        float4 b0 = *reinterpret_cast<const float4*>(fc1b + tn * 8);
        float4 b1 = *reinterpret_cast<const float4*>(fc1b + tn * 8 + 4);
        const float bj[8] = {b0.x, b0.y, b0.z, b0.w, b1.x, b1.y, b1.z, b1.w};
#pragma unroll
        for (int i = 0; i < 4; ++i)
#pragma unroll
            for (int j = 0; j < 8; ++j) { accL[i][j] += bj[j]; accH[i][j] += bj[j]; }
    }
    writeback_h();
    __syncthreads();

    // ---- 128 recurrence steps, h resident in LDS ----
#pragma unroll 1
    for (int s = 0; s < 128; ++s) {
        run_nt(Whh);                       // acc = h @ W_hh (barrier-closed)
#pragma unroll
        for (int i = 0; i < 4; ++i)
#pragma unroll
            for (int j = 0; j < 8; ++j) {
                accL[i][j] = tanh_xla(accL[i][j]);
                accH[i][j] = tanh_xla(accH[i][j]);
            }
        writeback_h();
        __syncthreads();
    }

    // ---- final h -> global (acc holds h_128 fragments) ----
#pragma unroll
    for (int i = 0; i < 4; ++i) {
        const long rL = row0 + tm * 4 + i;
        const long rH = rL + 64;
        *reinterpret_cast<float4*>(&hF[rL * Hd + tn * 8]) =
            make_float4(accL[i][0], accL[i][1], accL[i][2], accL[i][3]);
        *reinterpret_cast<float4*>(&hF[rL * Hd + tn * 8 + 4]) =
            make_float4(accL[i][4], accL[i][5], accL[i][6], accL[i][7]);
        *reinterpret_cast<float4*>(&hF[rH * Hd + tn * 8]) =
            make_float4(accH[i][0], accH[i][1], accH[i][2], accH[i][3]);
        *reinterpret_cast<float4*>(&hF[rH * Hd + tn * 8 + 4]) =
            make_float4(accH[i][4], accH[i][5], accH[i][6], accH[i][7]);
    }

    // ---- fc2: out = h @ fc2_w^T + fc2_b ----
    run_t(fc2w);
    {
        float4 b0 = *reinterpret_cast<const float4*>(fc2b + tn * 8);
        float4 b1 = *reinterpret_cast<const float4*>(fc2b + tn * 8 + 4);
        const float bj[8] = {b0.x, b0.y, b0.z, b0.w, b1.x, b1.y, b1.z, b1.w};
#pragma unroll
        for (int i = 0; i < 4; ++i)
#pragma unroll
            for (int j = 0; j < 8; ++j) { accL[i][j] += bj[j]; accH[i][j] += bj[j]; }
    }
#pragma unroll
    for (int i = 0; i < 4; ++i) {
        const long rL = row0 + tm * 4 + i;
        const long rH = rL + 64;
        *reinterpret_cast<float4*>(&outF[rL * Hd + tn * 8]) =
            make_float4(accL[i][0], accL[i][1], accL[i][2], accL[i][3]);
        *reinterpret_cast<float4*>(&outF[rL * Hd + tn * 8 + 4]) =
            make_float4(accL[i][4], accL[i][5], accL[i][6], accL[i][7]);
        *reinterpret_cast<float4*>(&outF[rH * Hd + tn * 8]) =
            make_float4(accH[i][0], accH[i][1], accH[i][2], accH[i][3]);
        *reinterpret_cast<float4*>(&outF[rH * Hd + tn * 8 + 4]) =
            make_float4(accH[i][4], accH[i][5], accH[i][6], accH[i][7]);
    }
}

extern "C" void kernel_launch(void* const* d_in, const int* in_sizes, int n_in,
                              void* d_out, int out_size, void* d_ws, size_t ws_size,
                              hipStream_t stream) {
    const float* x     = (const float*)d_in[0];
    const float* W_hh  = (const float*)d_in[1];
    const float* fc1_w = (const float*)d_in[2];
    const float* fc1_b = (const float*)d_in[3];
    const float* fc2_w = (const float*)d_in[4];
    const float* fc2_b = (const float*)d_in[5];
    // d_in[6] = steps (device scalar); fixed at 128 per the reference.

    const int B = in_sizes[0] / Hd;        // 65536
    float* out = (float*)d_out;            // [B][256]
    float* h   = out + (long)B * Hd;       // [B][256] second tuple output

    rnn_fused<<<dim3(B / BM), dim3(THREADS), 0, stream>>>(
        x, W_hh, fc1_w, fc1_b, fc2_w, fc2_b, out, h);
}